// Round 6
// baseline (1025.321 us; speedup 1.0000x reference)
//
#include <hip/hip_runtime.h>
#include <hip/hip_bf16.h>
#include <math.h>

// ---------------------------------------------------------------------------
// LSV Monte Carlo, round 12.
// R11 post-mortem: deleting VALU no longer helps (issue -17%, wall +12%) --
// the kernel stalls ~46% of wall and 4 waves/SIMD can't hide it. All rounds
// so far ran 16 waves/CU. R12 doubles wave parallelism:
//   1024 blocks x 512 threads, 16 paths/block -> 4 blocks/CU = 32 waves/CU
//   (8 waves/SIMD). VGPR forced <=64 via __launch_bounds__(512,8); per-wave
//   register demand DROPS vs R8 (one j-tile -> Af[4] = 16 VGPRs, one hedge
//   strike-tile -> Ah = 4).
// Duty map (R8's 3-phase structure kept):
//   A: waves 0-3 P1 (kc = w*4+quad) | all waves hedge (m=w>>1, st=w&1,
//      one MFMA each; st1 uses R11's row remap -> 2 sp) | wave 0 vnets
//   B: all waves main MFMA (j-tile = w; w=7 is the zero tile) | wave 7
//      ps_reduce
//   C: wave 4 R3 (serial SDE) | wave 5 CW1 fold | wave 6 CH fold
// 16-path-block numerics already validated by R10 (identical absmax).
// ---------------------------------------------------------------------------

#define MC      16384
#define NSTEP   96
#define BLOCK   512
#define NGROUP  1024
#define NPAIR   84

typedef short bf16x8 __attribute__((ext_vector_type(8)));
typedef float f32x4  __attribute__((ext_vector_type(4)));

union U8 { uint4 u; bf16x8 v; };
union BF2U { __hip_bfloat162 b; unsigned u; };

__device__ __forceinline__ unsigned bf16rne(float x) {   // setup-time only
    unsigned u = __float_as_uint(x);
    return (u + 0x7FFFu + ((u >> 16) & 1u)) >> 16;
}
__device__ __forceinline__ unsigned pk2(float lo, float hi) {
    BF2U t; t.b = __float22bfloat162_rn(make_float2(lo, hi));
    return t.u;
}
__device__ __forceinline__ float sp(float x) {
    return fmaxf(x, 0.f) + __logf(1.f + __expf(-fabsf(x)));
}

__global__ __launch_bounds__(BLOCK, 8)
void lsv_sim(const float* __restrict__ S0p,   const float* __restrict__ ratep,
             const float* __restrict__ z,     const float* __restrict__ zzg,
             const float* __restrict__ strikesg,
             const float* __restrict__ v0p,   const float* __restrict__ rhop,
             const float* __restrict__ svW1,  const float* __restrict__ svb1,
             const float* __restrict__ svW2,  const float* __restrict__ svb2,
             const float* __restrict__ svW3,  const float* __restrict__ svb3,
             const float* __restrict__ vhW1,  const float* __restrict__ vhb1,
             const float* __restrict__ vhW2,  const float* __restrict__ vhb2,
             const float* __restrict__ vdW1,  const float* __restrict__ vdb1,
             const float* __restrict__ vdW2,  const float* __restrict__ vdb2,
             const float* __restrict__ vvW1,  const float* __restrict__ vvb1,
             const float* __restrict__ vvW2,  const float* __restrict__ vvb2,
             const int*   __restrict__ mats,
             float* __restrict__ psum, float* __restrict__ psq)
{
    __shared__ __align__(16) unsigned short H1c[16 * 16 * 8]; // 4 KB [kc][path][8]
    __shared__ __align__(16) float W1f[16 * 32];              // 2 KB
    __shared__ __align__(16) float WH1f[16 * 32];             // 2 KB
    __shared__ __align__(16) float B2T[128], W3T[128];        // 1 KB
    __shared__ __align__(16) float RED[16 * 8];               // [path][wave]
    __shared__ float VDb[2][16], VVb[2][16];
    __shared__ float PSs[32], PSq[32];
    __shared__ __align__(16) float VW[128];
    __shared__ __align__(16) float4 STEP[NSTEP];              // {t0, h, sqh, disc0}
    __shared__ float D1T[NSTEP];                              // disc1
    __shared__ int   ITAB[NSTEP];                             // idx | (im<<8)
    __shared__ float ZT[16][97], ZZT[16][97];                 // 12.4 KB, padded
    __shared__ float SLOG[16], VST[16], SST[16], SLOGP[16], DSP[16];
    __shared__ __align__(16) float CW1[2][128];               // t0-fold: W1 net
    __shared__ __align__(16) float CH[2][128];                // t0-fold: hedge L1

    const int tid  = threadIdx.x;
    const int lane = tid & 63;
    const int w    = __builtin_amdgcn_readfirstlane(tid >> 6);  // 0..7
    const int quad = lane >> 4;
    const int col  = lane & 15;

    const int mh   = w >> 1;            // hedge maturity
    const int st   = w & 1;             // hedge strike tile
    const int path = col;               // this block's 16 paths
    const int kc   = (w & 3) * 4 + quad; // P1 k-chunk (waves 0-3)

    // ---- stage z/zz into LDS (coalesced) -----------------------------------
    {
        const size_t gbase = (size_t)blockIdx.x * 16 * NSTEP;
        for (int e = tid; e < 16 * NSTEP; e += BLOCK) {
            const int p = e / NSTEP, ii = e - p * NSTEP;
            ZT[p][ii]  = z  [gbase + e];
            ZZT[p][ii] = zzg[gbase + e];
        }
    }
    // ---- stage LDS tables --------------------------------------------------
    for (int e = tid; e < 128; e += BLOCK) {
        float v = 0.f;
        if      (e < 20)             v = vdW1[e];
        else if (e < 40)             v = vdb1[e - 20];
        else if (e < 60)             v = vdW2[e - 40];
        else if (e >= 64 && e < 84)  v = vvW1[e - 64];
        else if (e >= 84 && e < 104) v = vvb1[e - 84];
        else if (e >= 104 && e < 124)v = vvW2[e - 104];
        else if (e == 124)           v = vdb2[0];
        else if (e == 125)           v = vvb2[0];
        VW[e] = v;
        B2T[e] = (e < 100) ? svb2[e] : 0.f;
        W3T[e] = (e < 100) ? svW3[e] : 0.f;
    }
    for (int e = tid; e < 512; e += BLOCK) {       // W1f
        const int kc2 = e >> 5, r5 = e & 31, grp = r5 >> 3, kk = kc2 * 8 + (r5 & 7);
        float v = 0.f;
        if (kk < 100) v = (grp == 0) ? svW1[kk] : (grp == 1) ? svW1[100 + kk]
                        : (grp == 2) ? svW1[200 + kk] : svb1[kk];
        W1f[e] = v;
    }
    for (int e = tid; e < 512; e += BLOCK) {       // WH1f
        const int hq = e >> 5, r5 = e & 31, grp = r5 >> 3;
        const int hmm = hq >> 2, qq = hq & 3;
        const int j = qq * 8 + (r5 & 7);
        float v = 0.f;
        if (j < 20 && grp < 3)
            v = (grp == 0) ? vhW1[hmm * 40 + j] : (grp == 1) ? vhW1[hmm * 40 + 20 + j]
                                                : vhb1[hmm * 20 + j];
        WH1f[e] = v;
    }

    // ---- uniform setup -----------------------------------------------------
    const float rate  = ratep[0];
    const float S0    = S0p[0];
    const float rho_t = tanhf(rhop[0]);
    const float srho  = sqrtf(1.f - rho_t * rho_t);
    const float b3    = svb3[0];

    // ---- per-step uniform tables -------------------------------------------
    if (tid < NSTEP) {
        const int i = tid;
        const float t0 = (float)i       * (1.f / 365.f);
        const float t1 = (float)(i + 1) * (1.f / 365.f);
        const float h  = t1 - t0;
        STEP[i] = make_float4(t0, h, sqrtf(h), __expf(-rate * t0));
        D1T[i]  = __expf(-rate * t1);
        const int day = i + 1;
        const int m0 = mats[0], m1 = mats[1], m2 = mats[2], m3 = mats[3];
        const int idx = (day > m0) + (day > m1) + (day > m2);
        const int mi  = (idx == 0) ? m0 : (idx == 1) ? m1 : (idx == 2) ? m2 : m3;
        ITAB[i] = idx | ((day == mi) ? 256 : 0);
    }

    // ---- invariant A-fragments ---------------------------------------------
    // main: one j-tile per wave: A[m=j][k], j = w*16+col (w=7 -> zero tile)
    bf16x8 Af[4];
#pragma unroll
    for (int c = 0; c < 4; c++) {
        U8 tt;
#pragma unroll
        for (int e2 = 0; e2 < 4; e2++) {
            const int k0 = 32 * c + 8 * quad + 2 * e2;
            const int j  = w * 16 + col;
            const float v0 = (k0     < 100 && j < 100) ? svW2[k0 * 100 + j]       : 0.f;
            const float v1 = (k0 + 1 < 100 && j < 100) ? svW2[(k0 + 1) * 100 + j] : 0.f;
            (&tt.u.x)[e2] = bf16rne(v0) | (bf16rne(v1) << 16);
        }
        Af[c] = tt.v;
    }
    // hedge: one strike-tile per wave. st0: s=col (strikes 0-15).
    // st1 REMAPPED: s = 16+(col&3)*4+(col>>2) -> acc row r holds strike
    // 16+r*4+quad; the 5 real strikes live in rows 0-1.
    bf16x8 Ah;
    {
        U8 tt;
#pragma unroll
        for (int e2 = 0; e2 < 4; e2++) {
            const int j0 = 8 * quad + 2 * e2, j1 = j0 + 1;
            const int s  = (st == 0) ? col : (16 + (col & 3) * 4 + (col >> 2));
            const float v0 = (j0 < 20 && s < 21) ? vhW2[mh * 420 + j0 * 21 + s] : 0.f;
            const float v1 = (j1 < 20 && s < 21) ? vhW2[mh * 420 + j1 * 21 + s] : 0.f;
            (&tt.u.x)[e2] = bf16rne(v0) | (bf16rne(v1) << 16);
        }
        Ah = tt.v;
    }
    f32x4 c0h;
    float K0a[4];
#pragma unroll
    for (int r = 0; r < 4; r++) {
        const int s = (st == 0) ? (quad * 4 + r) : (16 + r * 4 + quad);
        c0h[r] = (s < 21) ? vhb2[mh * 21 + s] : 0.f;
        K0a[r] = (s < 21) ? strikesg[s] : 1e30f;
    }

    f32x4 cv0 = {0.f, 0.f, 0.f, 0.f};

    __syncthreads();          // tables staged

    // ---- step-0 folds + LDS state init -------------------------------------
    if (tid < 128) {
        const float t00 = STEP[0].x;
        const int kk = tid;
        CW1[0][kk] = fmaf(t00, W1f[(kk >> 3) * 32 + (kk & 7)],
                               W1f[(kk >> 3) * 32 + 24 + (kk & 7)]);
    } else if (tid < 256) {
        const float t00 = STEP[0].x;
        const int e = tid - 128;
        CH[0][e] = fmaf(t00, WH1f[(e >> 3) * 32 + (e & 7)],
                             WH1f[(e >> 3) * 32 + 16 + (e & 7)]);
    }
    if (tid < 16) {
        SLOG[tid] = __logf(S0);
        SST[tid]  = __expf(__logf(S0));
        VST[tid]  = (1.f / (1.f + __expf(-v0p[0]))) * 0.5f;
    }

    __syncthreads();          // folds + state visible

    // invariant epilogue + hedge-L1 weights -> registers
    const int j0e = w * 16 + quad * 4;
    const float4 b2a = *reinterpret_cast<const float4*>(B2T + j0e);
    const float4 w3a = *reinterpret_cast<const float4*>(W3T + j0e);
    const float4 wsA = *reinterpret_cast<const float4*>(WH1f + (mh * 4 + quad) * 32 + 8);
    const float4 wsB = *reinterpret_cast<const float4*>(WH1f + (mh * 4 + quad) * 32 + 12);

    auto hedge_step = [&](int ip) {
        const int iv   = ITAB[ip];
        const int idxp = iv & 0xff;
        if (mh >= idxp) {
            const int hb = ip & 1;
            const float slp = SLOGP[path];
            U8 b;
            {
                const float4 ch4 = *reinterpret_cast<const float4*>(&CH[hb][(mh * 4 + quad) * 8]);
                (&b.u.x)[0] = pk2(fmaxf(ch4.x + slp * wsA.x, 0.f),
                                  fmaxf(ch4.y + slp * wsA.y, 0.f));
                (&b.u.x)[1] = pk2(fmaxf(ch4.z + slp * wsA.z, 0.f),
                                  fmaxf(ch4.w + slp * wsA.w, 0.f));
            }
            {
                const float4 ch4 = *reinterpret_cast<const float4*>(&CH[hb][(mh * 4 + quad) * 8 + 4]);
                (&b.u.x)[2] = pk2(fmaxf(ch4.x + slp * wsB.x, 0.f),
                                  fmaxf(ch4.y + slp * wsB.y, 0.f));
                (&b.u.x)[3] = pk2(fmaxf(ch4.z + slp * wsB.z, 0.f),
                                  fmaxf(ch4.w + slp * wsB.w, 0.f));
            }
            const f32x4 D = __builtin_amdgcn_mfma_f32_16x16x32_bf16(Ah, b.v, c0h, 0, 0, 0);
            const float dsP = DSP[path];
            if (st == 0) {
#pragma unroll
                for (int r = 0; r < 4; r++) cv0[r] += sp(D[r]) * dsP;
            } else {
#pragma unroll
                for (int r = 0; r < 2; r++) cv0[r] += sp(D[r]) * dsP;
            }
            if ((iv & 256) && mh == idxp) {
                const float Sp  = SST[path];
                const float d1p = D1T[ip];
                if (st == 0) {
                    float p0[4], q0[4];
#pragma unroll
                    for (int r = 0; r < 4; r++) {
                        p0[r] = d1p * fmaxf(Sp - K0a[r], 0.f) - cv0[r];
                        q0[r] = p0[r] * p0[r];
                    }
#pragma unroll
                    for (int o = 1; o <= 8; o <<= 1) {
#pragma unroll
                        for (int r = 0; r < 4; r++) {
                            p0[r] += __shfl_xor(p0[r], o);
                            q0[r] += __shfl_xor(q0[r], o);
                        }
                    }
                    if (col == 0) {
#pragma unroll
                        for (int r = 0; r < 4; r++) {
                            const int s0 = quad * 4 + r;
                            PSs[s0] = p0[r];  PSq[s0] = q0[r];
                        }
                    }
                } else {
                    float p0[2], q0[2];
#pragma unroll
                    for (int r = 0; r < 2; r++) {
                        p0[r] = d1p * fmaxf(Sp - K0a[r], 0.f) - cv0[r];
                        q0[r] = p0[r] * p0[r];
                    }
#pragma unroll
                    for (int o = 1; o <= 8; o <<= 1) {
#pragma unroll
                        for (int r = 0; r < 2; r++) {
                            p0[r] += __shfl_xor(p0[r], o);
                            q0[r] += __shfl_xor(q0[r], o);
                        }
                    }
                    if (col == 0) {
#pragma unroll
                        for (int r = 0; r < 2; r++) {
                            const int s1 = 16 + r * 4 + quad;
                            if (s1 < 21) { PSs[s1] = p0[r];  PSq[s1] = q0[r]; }
                        }
                    }
                }
            }
        }
    };

    auto ps_reduce = [&](int ip) {
        if (w == 7) {
            const int iv = ITAB[ip];
            if (iv & 256) {
                const int s = lane & 31;
                if (s < 21) {
                    const float* src = (lane >= 32) ? &PSq[0] : &PSs[0];
                    float* dst = (lane >= 32) ? psq : psum;
                    dst[((iv & 0xff) * 21 + s) * NGROUP + blockIdx.x] = src[s];
                }
            }
        }
    };

    for (int i = 0; i < NSTEP; i++) {
        const int buf = i & 1;

        // ===== Phase A: P1 (waves 0-3) | lagged hedge (all) | vnets (w0) ====
        if (w < 4) {
            const float slp = SLOG[path];
            const float vp  = VST[path];
            const float* Wp = W1f + kc * 32;
            uint4 o;
#pragma unroll
            for (int hh = 0; hh < 2; hh++) {
                const float4 b4 = *reinterpret_cast<const float4*>(Wp + 8 + hh * 4);
                const float4 c4 = *reinterpret_cast<const float4*>(Wp + 16 + hh * 4);
                const float4 cw = *reinterpret_cast<const float4*>(&CW1[buf][kc * 8 + hh * 4]);
                const float x0 = fmaxf(cw.x + slp * b4.x + vp * c4.x, 0.f);
                const float x1 = fmaxf(cw.y + slp * b4.y + vp * c4.y, 0.f);
                const float x2 = fmaxf(cw.z + slp * b4.z + vp * c4.z, 0.f);
                const float x3 = fmaxf(cw.w + slp * b4.w + vp * c4.w, 0.f);
                (&o.x)[2 * hh]     = pk2(x0, x1);
                (&o.x)[2 * hh + 1] = pk2(x2, x3);
            }
            *reinterpret_cast<uint4*>(H1c + (kc * 16 + path) * 8) = o;
        }
        if (i > 0) hedge_step(i - 1);
        if (w == 0 && lane < 32) {            // vd (lanes 0-15) / vv (16-31)
            const int p = lane & 15;
            const float Vp = VST[p];
            const float* bw = VW + ((lane >= 16) ? 64 : 0);
            float a2 = 0.f;
#pragma unroll
            for (int q5 = 0; q5 < 5; q5++) {
                const float4 w1 = *reinterpret_cast<const float4*>(bw + 4 * q5);
                const float4 b1 = *reinterpret_cast<const float4*>(bw + 20 + 4 * q5);
                const float4 w2 = *reinterpret_cast<const float4*>(bw + 40 + 4 * q5);
                a2 += fmaxf(Vp * w1.x + b1.x, 0.f) * w2.x;
                a2 += fmaxf(Vp * w1.y + b1.y, 0.f) * w2.y;
                a2 += fmaxf(Vp * w1.z + b1.z, 0.f) * w2.z;
                a2 += fmaxf(Vp * w1.w + b1.w, 0.f) * w2.w;
            }
            if (lane < 16) VDb[buf][p] = a2; else VVb[buf][p] = a2;
        }
        __syncthreads();

        // ===== Phase B: main MFMA (j-tile = w) | ps_reduce (w7) =============
        {
            f32x4 d0 = {0.f, 0.f, 0.f, 0.f};
#pragma unroll
            for (int c = 0; c < 4; c++) {
                const bf16x8 b = *reinterpret_cast<const bf16x8*>(
                    H1c + ((quad + 4 * c) * 16 + path) * 8);
                d0 = __builtin_amdgcn_mfma_f32_16x16x32_bf16(Af[c], b, d0, 0, 0, 0);
            }
            float acc = fmaxf(d0[0] + b2a.x, 0.f) * w3a.x
                      + fmaxf(d0[1] + b2a.y, 0.f) * w3a.y
                      + fmaxf(d0[2] + b2a.z, 0.f) * w3a.z
                      + fmaxf(d0[3] + b2a.w, 0.f) * w3a.w;
            acc += __shfl_xor(acc, 16);
            acc += __shfl_xor(acc, 32);
            if (quad == 0)
                RED[path * 8 + w] = acc;
        }
        if (i > 0) ps_reduce(i - 1);
        __syncthreads();

        // ===== Phase C: R3 (w4) | CW1 fold (w5) | CH fold (w6) ==============
        if (w == 4) {
            const int lp = lane & 15;
            const float4 r0 = *reinterpret_cast<const float4*>(RED + lp * 8);
            const float4 r1 = *reinterpret_cast<const float4*>(RED + lp * 8 + 4);
            const float pout = ((r0.x + r0.y) + (r0.z + r0.w))
                             + ((r1.x + r1.y) + (r1.z + r1.w));
            const float pd = sp(pout + b3);
            const float vdv = VDb[buf][lp] + VW[124];
            const float vvv = sp(VVb[buf][lp] + VW[125]);
            const float4 u  = STEP[i];
            const float sqh = u.z;
            const float zi  = ZT[lp][i];
            const float zzi = ZZT[lp][i];
            const float dW = sqh * zi;
            const float dB = rho_t * dW + srho * sqh * zzi;
            const float Vold = VST[lp];
            const float Sold = SST[lp];
            const float SlogO = SLOG[lp];
            const float Vn = Vold + vdv * u.y + vvv * dB;
            const float drift   = rate - 0.5f * pd * pd;
            const float diff    = pd * dW;
            const float drift_c = 1.f + fabsf(drift) * sqh;
            const float diff_c  = 1.f + fabsf(pd) * sqh;
            const float Sln = SlogO + __fdividef(drift * u.y, drift_c) + __fdividef(diff, diff_c);
            const float Sn  = __expf(Sln);
            const float dS  = D1T[i] * Sn - u.w * Sold;
            if (lane < 16) {
                SLOGP[lp] = SlogO;  DSP[lp] = dS;
                SLOG[lp]  = Sln;    SST[lp] = Sn;  VST[lp] = Vn;
            }
        } else if (w == 5 && i + 1 < NSTEP) {
            const float t0n = STEP[i + 1].x;
#pragma unroll
            for (int rep = 0; rep < 2; rep++) {
                const int kk = rep * 64 + lane;
                CW1[buf ^ 1][kk] = fmaf(t0n, W1f[(kk >> 3) * 32 + (kk & 7)],
                                             W1f[(kk >> 3) * 32 + 24 + (kk & 7)]);
            }
        } else if (w == 6 && i + 1 < NSTEP) {
            const float t0n = STEP[i + 1].x;
#pragma unroll
            for (int rep = 0; rep < 2; rep++) {
                const int e = rep * 64 + lane;
                CH[buf ^ 1][e] = fmaf(t0n, WH1f[(e >> 3) * 32 + (e & 7)],
                                           WH1f[(e >> 3) * 32 + 16 + (e & 7)]);
            }
        }
        __syncthreads();
    }

    hedge_step(NSTEP - 1);
    __syncthreads();
    ps_reduce(NSTEP - 1);
}

__global__ void lsv_finalize(const float* __restrict__ psum,
                             const float* __restrict__ psq,
                             float* __restrict__ out)
{
    const int t    = blockIdx.x;          // 0..NPAIR-1
    const int lane = threadIdx.x;         // 0..63
    float s = 0.f, q = 0.f;
    for (int b = lane; b < NGROUP; b += 64) {
        s += psum[t * NGROUP + b];
        q += psq [t * NGROUP + b];
    }
#pragma unroll
    for (int o = 1; o <= 32; o <<= 1) {
        s += __shfl_xor(s, o);
        q += __shfl_xor(q, o);
    }
    if (lane == 0) {
        const float mean = s * (1.0f / (float)MC);
        const float var  = (q - (float)MC * mean * mean) * (1.0f / (float)(MC - 1));
        out[t]         = mean;
        out[NPAIR + t] = var;
    }
}

extern "C" void kernel_launch(void* const* d_in, const int* in_sizes, int n_in,
                              void* d_out, int out_size, void* d_ws, size_t ws_size,
                              hipStream_t stream)
{
    const float* S0    = (const float*)d_in[0];
    const float* rate  = (const float*)d_in[1];
    const float* z     = (const float*)d_in[2];
    const float* zz    = (const float*)d_in[3];
    const float* strikes = (const float*)d_in[5];
    const float* v0    = (const float*)d_in[6];
    const float* rho   = (const float*)d_in[7];
    const float* svW1  = (const float*)d_in[8];
    const float* svb1  = (const float*)d_in[9];
    const float* svW2  = (const float*)d_in[10];
    const float* svb2  = (const float*)d_in[11];
    const float* svW3  = (const float*)d_in[12];
    const float* svb3  = (const float*)d_in[13];
    const float* vhW1  = (const float*)d_in[14];
    const float* vhb1  = (const float*)d_in[15];
    const float* vhW2  = (const float*)d_in[16];
    const float* vhb2  = (const float*)d_in[17];
    const float* vdW1  = (const float*)d_in[18];
    const float* vdb1  = (const float*)d_in[19];
    const float* vdW2  = (const float*)d_in[20];
    const float* vdb2  = (const float*)d_in[21];
    const float* vvW1  = (const float*)d_in[22];
    const float* vvb1  = (const float*)d_in[23];
    const float* vvW2  = (const float*)d_in[24];
    const float* vvb2  = (const float*)d_in[25];
    const int*   mats  = (const int*)d_in[26];

    float* psum = (float*)d_ws;
    float* psq  = psum + NPAIR * NGROUP;

    hipLaunchKernelGGL(lsv_sim, dim3(NGROUP), dim3(BLOCK), 0, stream,
                       S0, rate, z, zz, strikes, v0, rho,
                       svW1, svb1, svW2, svb2, svW3, svb3,
                       vhW1, vhb1, vhW2, vhb2,
                       vdW1, vdb1, vdW2, vdb2,
                       vvW1, vvb1, vvW2, vvb2,
                       mats, psum, psq);

    hipLaunchKernelGGL(lsv_finalize, dim3(NPAIR), dim3(64), 0, stream,
                       psum, psq, (float*)d_out);
}

// Round 7
// 441.206 us; speedup vs baseline: 2.3239x; 2.3239x over previous
//
#include <hip/hip_runtime.h>
#include <hip/hip_bf16.h>
#include <math.h>

// ---------------------------------------------------------------------------
// LSV Monte Carlo, round 13 = R12 structure, register clamp removed.
// R12 post-mortem: __launch_bounds__(512,8) forced VGPR=32 -> spills ->
// FETCH 2.6 GB, 952us. BUT occupancy hit 92% (4 blocks/CU resident): the
// occupancy lever works; only the clamp was wrong. Hardware residency
// follows ACTUAL VGPR count: at <=64 VGPR + 28KB LDS we get 4 blocks/CU x
// 8 waves = 32 waves/CU without any forcing.
//  * __launch_bounds__(512,4) (same bound under which R8's heavier set
//    compiled to exactly 64 VGPR; R12's per-wave set is strictly lighter).
//  * wave 7's main j-tile (j=112..127) is all-zero weights: skip its
//    4 MFMAs + epilogue; RED[path*8+7] pre-initialized to 0 once.
// Duty map unchanged from R12:
//   A: waves 0-3 P1 | all waves lagged hedge (m=w>>1, st=w&1; st1 row
//      remap -> 2 sp) | wave 0 vnets
//   B: waves 0-6 main MFMA (j-tile = w) | wave 7 ps_reduce
//   C: wave 4 R3 | wave 5 CW1 fold | wave 6 CH fold
// ---------------------------------------------------------------------------

#define MC      16384
#define NSTEP   96
#define BLOCK   512
#define NGROUP  1024
#define NPAIR   84

typedef short bf16x8 __attribute__((ext_vector_type(8)));
typedef float f32x4  __attribute__((ext_vector_type(4)));

union U8 { uint4 u; bf16x8 v; };
union BF2U { __hip_bfloat162 b; unsigned u; };

__device__ __forceinline__ unsigned bf16rne(float x) {   // setup-time only
    unsigned u = __float_as_uint(x);
    return (u + 0x7FFFu + ((u >> 16) & 1u)) >> 16;
}
__device__ __forceinline__ unsigned pk2(float lo, float hi) {
    BF2U t; t.b = __float22bfloat162_rn(make_float2(lo, hi));
    return t.u;
}
__device__ __forceinline__ float sp(float x) {
    return fmaxf(x, 0.f) + __logf(1.f + __expf(-fabsf(x)));
}

__global__ __launch_bounds__(BLOCK, 4)
void lsv_sim(const float* __restrict__ S0p,   const float* __restrict__ ratep,
             const float* __restrict__ z,     const float* __restrict__ zzg,
             const float* __restrict__ strikesg,
             const float* __restrict__ v0p,   const float* __restrict__ rhop,
             const float* __restrict__ svW1,  const float* __restrict__ svb1,
             const float* __restrict__ svW2,  const float* __restrict__ svb2,
             const float* __restrict__ svW3,  const float* __restrict__ svb3,
             const float* __restrict__ vhW1,  const float* __restrict__ vhb1,
             const float* __restrict__ vhW2,  const float* __restrict__ vhb2,
             const float* __restrict__ vdW1,  const float* __restrict__ vdb1,
             const float* __restrict__ vdW2,  const float* __restrict__ vdb2,
             const float* __restrict__ vvW1,  const float* __restrict__ vvb1,
             const float* __restrict__ vvW2,  const float* __restrict__ vvb2,
             const int*   __restrict__ mats,
             float* __restrict__ psum, float* __restrict__ psq)
{
    __shared__ __align__(16) unsigned short H1c[16 * 16 * 8]; // 4 KB [kc][path][8]
    __shared__ __align__(16) float W1f[16 * 32];              // 2 KB
    __shared__ __align__(16) float WH1f[16 * 32];             // 2 KB
    __shared__ __align__(16) float B2T[128], W3T[128];        // 1 KB
    __shared__ __align__(16) float RED[16 * 8];               // [path][wave]
    __shared__ float VDb[2][16], VVb[2][16];
    __shared__ float PSs[32], PSq[32];
    __shared__ __align__(16) float VW[128];
    __shared__ __align__(16) float4 STEP[NSTEP];              // {t0, h, sqh, disc0}
    __shared__ float D1T[NSTEP];                              // disc1
    __shared__ int   ITAB[NSTEP];                             // idx | (im<<8)
    __shared__ float ZT[16][97], ZZT[16][97];                 // 12.4 KB, padded
    __shared__ float SLOG[16], VST[16], SST[16], SLOGP[16], DSP[16];
    __shared__ __align__(16) float CW1[2][128];               // t0-fold: W1 net
    __shared__ __align__(16) float CH[2][128];                // t0-fold: hedge L1

    const int tid  = threadIdx.x;
    const int lane = tid & 63;
    const int w    = __builtin_amdgcn_readfirstlane(tid >> 6);  // 0..7
    const int quad = lane >> 4;
    const int col  = lane & 15;

    const int mh   = w >> 1;            // hedge maturity
    const int st   = w & 1;             // hedge strike tile
    const int path = col;               // this block's 16 paths
    const int kc   = (w & 3) * 4 + quad; // P1 k-chunk (waves 0-3)

    // ---- stage z/zz into LDS (coalesced) -----------------------------------
    {
        const size_t gbase = (size_t)blockIdx.x * 16 * NSTEP;
        for (int e = tid; e < 16 * NSTEP; e += BLOCK) {
            const int p = e / NSTEP, ii = e - p * NSTEP;
            ZT[p][ii]  = z  [gbase + e];
            ZZT[p][ii] = zzg[gbase + e];
        }
    }
    // ---- stage LDS tables --------------------------------------------------
    for (int e = tid; e < 128; e += BLOCK) {
        float v = 0.f;
        if      (e < 20)             v = vdW1[e];
        else if (e < 40)             v = vdb1[e - 20];
        else if (e < 60)             v = vdW2[e - 40];
        else if (e >= 64 && e < 84)  v = vvW1[e - 64];
        else if (e >= 84 && e < 104) v = vvb1[e - 84];
        else if (e >= 104 && e < 124)v = vvW2[e - 104];
        else if (e == 124)           v = vdb2[0];
        else if (e == 125)           v = vvb2[0];
        VW[e] = v;
        B2T[e] = (e < 100) ? svb2[e] : 0.f;
        W3T[e] = (e < 100) ? svW3[e] : 0.f;
    }
    for (int e = tid; e < 512; e += BLOCK) {       // W1f
        const int kc2 = e >> 5, r5 = e & 31, grp = r5 >> 3, kk = kc2 * 8 + (r5 & 7);
        float v = 0.f;
        if (kk < 100) v = (grp == 0) ? svW1[kk] : (grp == 1) ? svW1[100 + kk]
                        : (grp == 2) ? svW1[200 + kk] : svb1[kk];
        W1f[e] = v;
    }
    for (int e = tid; e < 512; e += BLOCK) {       // WH1f
        const int hq = e >> 5, r5 = e & 31, grp = r5 >> 3;
        const int hmm = hq >> 2, qq = hq & 3;
        const int j = qq * 8 + (r5 & 7);
        float v = 0.f;
        if (j < 20 && grp < 3)
            v = (grp == 0) ? vhW1[hmm * 40 + j] : (grp == 1) ? vhW1[hmm * 40 + 20 + j]
                                                : vhb1[hmm * 20 + j];
        WH1f[e] = v;
    }

    // ---- uniform setup -----------------------------------------------------
    const float rate  = ratep[0];
    const float S0    = S0p[0];
    const float rho_t = tanhf(rhop[0]);
    const float srho  = sqrtf(1.f - rho_t * rho_t);
    const float b3    = svb3[0];

    // ---- per-step uniform tables -------------------------------------------
    if (tid < NSTEP) {
        const int i = tid;
        const float t0 = (float)i       * (1.f / 365.f);
        const float t1 = (float)(i + 1) * (1.f / 365.f);
        const float h  = t1 - t0;
        STEP[i] = make_float4(t0, h, sqrtf(h), __expf(-rate * t0));
        D1T[i]  = __expf(-rate * t1);
        const int day = i + 1;
        const int m0 = mats[0], m1 = mats[1], m2 = mats[2], m3 = mats[3];
        const int idx = (day > m0) + (day > m1) + (day > m2);
        const int mi  = (idx == 0) ? m0 : (idx == 1) ? m1 : (idx == 2) ? m2 : m3;
        ITAB[i] = idx | ((day == mi) ? 256 : 0);
    }

    // ---- invariant A-fragments ---------------------------------------------
    // main: one j-tile per wave: A[m=j][k], j = w*16+col (w=7: all-zero tile,
    // skipped in phase B)
    bf16x8 Af[4];
#pragma unroll
    for (int c = 0; c < 4; c++) {
        U8 tt;
#pragma unroll
        for (int e2 = 0; e2 < 4; e2++) {
            const int k0 = 32 * c + 8 * quad + 2 * e2;
            const int j  = w * 16 + col;
            const float v0 = (k0     < 100 && j < 100) ? svW2[k0 * 100 + j]       : 0.f;
            const float v1 = (k0 + 1 < 100 && j < 100) ? svW2[(k0 + 1) * 100 + j] : 0.f;
            (&tt.u.x)[e2] = bf16rne(v0) | (bf16rne(v1) << 16);
        }
        Af[c] = tt.v;
    }
    // hedge: one strike-tile per wave. st0: s=col (strikes 0-15).
    // st1 REMAPPED: s = 16+(col&3)*4+(col>>2) -> acc row r holds strike
    // 16+r*4+quad; the 5 real strikes live in rows 0-1.
    bf16x8 Ah;
    {
        U8 tt;
#pragma unroll
        for (int e2 = 0; e2 < 4; e2++) {
            const int j0 = 8 * quad + 2 * e2, j1 = j0 + 1;
            const int s  = (st == 0) ? col : (16 + (col & 3) * 4 + (col >> 2));
            const float v0 = (j0 < 20 && s < 21) ? vhW2[mh * 420 + j0 * 21 + s] : 0.f;
            const float v1 = (j1 < 20 && s < 21) ? vhW2[mh * 420 + j1 * 21 + s] : 0.f;
            (&tt.u.x)[e2] = bf16rne(v0) | (bf16rne(v1) << 16);
        }
        Ah = tt.v;
    }
    f32x4 c0h;
    float K0a[4];
#pragma unroll
    for (int r = 0; r < 4; r++) {
        const int s = (st == 0) ? (quad * 4 + r) : (16 + r * 4 + quad);
        c0h[r] = (s < 21) ? vhb2[mh * 21 + s] : 0.f;
        K0a[r] = (s < 21) ? strikesg[s] : 1e30f;
    }

    f32x4 cv0 = {0.f, 0.f, 0.f, 0.f};

    __syncthreads();          // tables staged

    // ---- step-0 folds + LDS state init -------------------------------------
    if (tid < 128) {
        const float t00 = STEP[0].x;
        const int kk = tid;
        CW1[0][kk] = fmaf(t00, W1f[(kk >> 3) * 32 + (kk & 7)],
                               W1f[(kk >> 3) * 32 + 24 + (kk & 7)]);
    } else if (tid < 256) {
        const float t00 = STEP[0].x;
        const int e = tid - 128;
        CH[0][e] = fmaf(t00, WH1f[(e >> 3) * 32 + (e & 7)],
                             WH1f[(e >> 3) * 32 + 16 + (e & 7)]);
    }
    if (tid < 16) {
        SLOG[tid] = __logf(S0);
        SST[tid]  = __expf(__logf(S0));
        VST[tid]  = (1.f / (1.f + __expf(-v0p[0]))) * 0.5f;
        RED[tid * 8 + 7] = 0.f;          // wave-7 j-tile is all-zero: constant
    }

    __syncthreads();          // folds + state visible

    // invariant epilogue + hedge-L1 weights -> registers
    const int j0e = w * 16 + quad * 4;
    const float4 b2a = *reinterpret_cast<const float4*>(B2T + j0e);
    const float4 w3a = *reinterpret_cast<const float4*>(W3T + j0e);
    const float4 wsA = *reinterpret_cast<const float4*>(WH1f + (mh * 4 + quad) * 32 + 8);
    const float4 wsB = *reinterpret_cast<const float4*>(WH1f + (mh * 4 + quad) * 32 + 12);

    auto hedge_step = [&](int ip) {
        const int iv   = ITAB[ip];
        const int idxp = iv & 0xff;
        if (mh >= idxp) {
            const int hb = ip & 1;
            const float slp = SLOGP[path];
            U8 b;
            {
                const float4 ch4 = *reinterpret_cast<const float4*>(&CH[hb][(mh * 4 + quad) * 8]);
                (&b.u.x)[0] = pk2(fmaxf(ch4.x + slp * wsA.x, 0.f),
                                  fmaxf(ch4.y + slp * wsA.y, 0.f));
                (&b.u.x)[1] = pk2(fmaxf(ch4.z + slp * wsA.z, 0.f),
                                  fmaxf(ch4.w + slp * wsA.w, 0.f));
            }
            {
                const float4 ch4 = *reinterpret_cast<const float4*>(&CH[hb][(mh * 4 + quad) * 8 + 4]);
                (&b.u.x)[2] = pk2(fmaxf(ch4.x + slp * wsB.x, 0.f),
                                  fmaxf(ch4.y + slp * wsB.y, 0.f));
                (&b.u.x)[3] = pk2(fmaxf(ch4.z + slp * wsB.z, 0.f),
                                  fmaxf(ch4.w + slp * wsB.w, 0.f));
            }
            const f32x4 D = __builtin_amdgcn_mfma_f32_16x16x32_bf16(Ah, b.v, c0h, 0, 0, 0);
            const float dsP = DSP[path];
            if (st == 0) {
#pragma unroll
                for (int r = 0; r < 4; r++) cv0[r] += sp(D[r]) * dsP;
            } else {
#pragma unroll
                for (int r = 0; r < 2; r++) cv0[r] += sp(D[r]) * dsP;
            }
            if ((iv & 256) && mh == idxp) {
                const float Sp  = SST[path];
                const float d1p = D1T[ip];
                if (st == 0) {
                    float p0[4], q0[4];
#pragma unroll
                    for (int r = 0; r < 4; r++) {
                        p0[r] = d1p * fmaxf(Sp - K0a[r], 0.f) - cv0[r];
                        q0[r] = p0[r] * p0[r];
                    }
#pragma unroll
                    for (int o = 1; o <= 8; o <<= 1) {
#pragma unroll
                        for (int r = 0; r < 4; r++) {
                            p0[r] += __shfl_xor(p0[r], o);
                            q0[r] += __shfl_xor(q0[r], o);
                        }
                    }
                    if (col == 0) {
#pragma unroll
                        for (int r = 0; r < 4; r++) {
                            const int s0 = quad * 4 + r;
                            PSs[s0] = p0[r];  PSq[s0] = q0[r];
                        }
                    }
                } else {
                    float p0[2], q0[2];
#pragma unroll
                    for (int r = 0; r < 2; r++) {
                        p0[r] = d1p * fmaxf(Sp - K0a[r], 0.f) - cv0[r];
                        q0[r] = p0[r] * p0[r];
                    }
#pragma unroll
                    for (int o = 1; o <= 8; o <<= 1) {
#pragma unroll
                        for (int r = 0; r < 2; r++) {
                            p0[r] += __shfl_xor(p0[r], o);
                            q0[r] += __shfl_xor(q0[r], o);
                        }
                    }
                    if (col == 0) {
#pragma unroll
                        for (int r = 0; r < 2; r++) {
                            const int s1 = 16 + r * 4 + quad;
                            if (s1 < 21) { PSs[s1] = p0[r];  PSq[s1] = q0[r]; }
                        }
                    }
                }
            }
        }
    };

    auto ps_reduce = [&](int ip) {
        if (w == 7) {
            const int iv = ITAB[ip];
            if (iv & 256) {
                const int s = lane & 31;
                if (s < 21) {
                    const float* src = (lane >= 32) ? &PSq[0] : &PSs[0];
                    float* dst = (lane >= 32) ? psq : psum;
                    dst[((iv & 0xff) * 21 + s) * NGROUP + blockIdx.x] = src[s];
                }
            }
        }
    };

    for (int i = 0; i < NSTEP; i++) {
        const int buf = i & 1;

        // ===== Phase A: P1 (waves 0-3) | lagged hedge (all) | vnets (w0) ====
        if (w < 4) {
            const float slp = SLOG[path];
            const float vp  = VST[path];
            const float* Wp = W1f + kc * 32;
            uint4 o;
#pragma unroll
            for (int hh = 0; hh < 2; hh++) {
                const float4 b4 = *reinterpret_cast<const float4*>(Wp + 8 + hh * 4);
                const float4 c4 = *reinterpret_cast<const float4*>(Wp + 16 + hh * 4);
                const float4 cw = *reinterpret_cast<const float4*>(&CW1[buf][kc * 8 + hh * 4]);
                const float x0 = fmaxf(cw.x + slp * b4.x + vp * c4.x, 0.f);
                const float x1 = fmaxf(cw.y + slp * b4.y + vp * c4.y, 0.f);
                const float x2 = fmaxf(cw.z + slp * b4.z + vp * c4.z, 0.f);
                const float x3 = fmaxf(cw.w + slp * b4.w + vp * c4.w, 0.f);
                (&o.x)[2 * hh]     = pk2(x0, x1);
                (&o.x)[2 * hh + 1] = pk2(x2, x3);
            }
            *reinterpret_cast<uint4*>(H1c + (kc * 16 + path) * 8) = o;
        }
        if (i > 0) hedge_step(i - 1);
        if (w == 0 && lane < 32) {            // vd (lanes 0-15) / vv (16-31)
            const int p = lane & 15;
            const float Vp = VST[p];
            const float* bw = VW + ((lane >= 16) ? 64 : 0);
            float a2 = 0.f;
#pragma unroll
            for (int q5 = 0; q5 < 5; q5++) {
                const float4 w1 = *reinterpret_cast<const float4*>(bw + 4 * q5);
                const float4 b1 = *reinterpret_cast<const float4*>(bw + 20 + 4 * q5);
                const float4 w2 = *reinterpret_cast<const float4*>(bw + 40 + 4 * q5);
                a2 += fmaxf(Vp * w1.x + b1.x, 0.f) * w2.x;
                a2 += fmaxf(Vp * w1.y + b1.y, 0.f) * w2.y;
                a2 += fmaxf(Vp * w1.z + b1.z, 0.f) * w2.z;
                a2 += fmaxf(Vp * w1.w + b1.w, 0.f) * w2.w;
            }
            if (lane < 16) VDb[buf][p] = a2; else VVb[buf][p] = a2;
        }
        __syncthreads();

        // ===== Phase B: main MFMA (j-tile = w, waves 0-6) | ps_reduce (w7) ==
        if (w < 7) {
            f32x4 d0 = {0.f, 0.f, 0.f, 0.f};
#pragma unroll
            for (int c = 0; c < 4; c++) {
                const bf16x8 b = *reinterpret_cast<const bf16x8*>(
                    H1c + ((quad + 4 * c) * 16 + path) * 8);
                d0 = __builtin_amdgcn_mfma_f32_16x16x32_bf16(Af[c], b, d0, 0, 0, 0);
            }
            float acc = fmaxf(d0[0] + b2a.x, 0.f) * w3a.x
                      + fmaxf(d0[1] + b2a.y, 0.f) * w3a.y
                      + fmaxf(d0[2] + b2a.z, 0.f) * w3a.z
                      + fmaxf(d0[3] + b2a.w, 0.f) * w3a.w;
            acc += __shfl_xor(acc, 16);
            acc += __shfl_xor(acc, 32);
            if (quad == 0)
                RED[path * 8 + w] = acc;
        }
        if (i > 0) ps_reduce(i - 1);
        __syncthreads();

        // ===== Phase C: R3 (w4) | CW1 fold (w5) | CH fold (w6) ==============
        if (w == 4) {
            const int lp = lane & 15;
            const float4 r0 = *reinterpret_cast<const float4*>(RED + lp * 8);
            const float4 r1 = *reinterpret_cast<const float4*>(RED + lp * 8 + 4);
            const float pout = ((r0.x + r0.y) + (r0.z + r0.w))
                             + ((r1.x + r1.y) + (r1.z + r1.w));
            const float pd = sp(pout + b3);
            const float vdv = VDb[buf][lp] + VW[124];
            const float vvv = sp(VVb[buf][lp] + VW[125]);
            const float4 u  = STEP[i];
            const float sqh = u.z;
            const float zi  = ZT[lp][i];
            const float zzi = ZZT[lp][i];
            const float dW = sqh * zi;
            const float dB = rho_t * dW + srho * sqh * zzi;
            const float Vold = VST[lp];
            const float Sold = SST[lp];
            const float SlogO = SLOG[lp];
            const float Vn = Vold + vdv * u.y + vvv * dB;
            const float drift   = rate - 0.5f * pd * pd;
            const float diff    = pd * dW;
            const float drift_c = 1.f + fabsf(drift) * sqh;
            const float diff_c  = 1.f + fabsf(pd) * sqh;
            const float Sln = SlogO + __fdividef(drift * u.y, drift_c) + __fdividef(diff, diff_c);
            const float Sn  = __expf(Sln);
            const float dS  = D1T[i] * Sn - u.w * Sold;
            if (lane < 16) {
                SLOGP[lp] = SlogO;  DSP[lp] = dS;
                SLOG[lp]  = Sln;    SST[lp] = Sn;  VST[lp] = Vn;
            }
        } else if (w == 5 && i + 1 < NSTEP) {
            const float t0n = STEP[i + 1].x;
#pragma unroll
            for (int rep = 0; rep < 2; rep++) {
                const int kk = rep * 64 + lane;
                CW1[buf ^ 1][kk] = fmaf(t0n, W1f[(kk >> 3) * 32 + (kk & 7)],
                                             W1f[(kk >> 3) * 32 + 24 + (kk & 7)]);
            }
        } else if (w == 6 && i + 1 < NSTEP) {
            const float t0n = STEP[i + 1].x;
#pragma unroll
            for (int rep = 0; rep < 2; rep++) {
                const int e = rep * 64 + lane;
                CH[buf ^ 1][e] = fmaf(t0n, WH1f[(e >> 3) * 32 + (e & 7)],
                                           WH1f[(e >> 3) * 32 + 16 + (e & 7)]);
            }
        }
        __syncthreads();
    }

    hedge_step(NSTEP - 1);
    __syncthreads();
    ps_reduce(NSTEP - 1);
}

__global__ void lsv_finalize(const float* __restrict__ psum,
                             const float* __restrict__ psq,
                             float* __restrict__ out)
{
    const int t    = blockIdx.x;          // 0..NPAIR-1
    const int lane = threadIdx.x;         // 0..63
    float s = 0.f, q = 0.f;
    for (int b = lane; b < NGROUP; b += 64) {
        s += psum[t * NGROUP + b];
        q += psq [t * NGROUP + b];
    }
#pragma unroll
    for (int o = 1; o <= 32; o <<= 1) {
        s += __shfl_xor(s, o);
        q += __shfl_xor(q, o);
    }
    if (lane == 0) {
        const float mean = s * (1.0f / (float)MC);
        const float var  = (q - (float)MC * mean * mean) * (1.0f / (float)(MC - 1));
        out[t]         = mean;
        out[NPAIR + t] = var;
    }
}

extern "C" void kernel_launch(void* const* d_in, const int* in_sizes, int n_in,
                              void* d_out, int out_size, void* d_ws, size_t ws_size,
                              hipStream_t stream)
{
    const float* S0    = (const float*)d_in[0];
    const float* rate  = (const float*)d_in[1];
    const float* z     = (const float*)d_in[2];
    const float* zz    = (const float*)d_in[3];
    const float* strikes = (const float*)d_in[5];
    const float* v0    = (const float*)d_in[6];
    const float* rho   = (const float*)d_in[7];
    const float* svW1  = (const float*)d_in[8];
    const float* svb1  = (const float*)d_in[9];
    const float* svW2  = (const float*)d_in[10];
    const float* svb2  = (const float*)d_in[11];
    const float* svW3  = (const float*)d_in[12];
    const float* svb3  = (const float*)d_in[13];
    const float* vhW1  = (const float*)d_in[14];
    const float* vhb1  = (const float*)d_in[15];
    const float* vhW2  = (const float*)d_in[16];
    const float* vhb2  = (const float*)d_in[17];
    const float* vdW1  = (const float*)d_in[18];
    const float* vdb1  = (const float*)d_in[19];
    const float* vdW2  = (const float*)d_in[20];
    const float* vdb2  = (const float*)d_in[21];
    const float* vvW1  = (const float*)d_in[22];
    const float* vvb1  = (const float*)d_in[23];
    const float* vvW2  = (const float*)d_in[24];
    const float* vvb2  = (const float*)d_in[25];
    const int*   mats  = (const int*)d_in[26];

    float* psum = (float*)d_ws;
    float* psq  = psum + NPAIR * NGROUP;

    hipLaunchKernelGGL(lsv_sim, dim3(NGROUP), dim3(BLOCK), 0, stream,
                       S0, rate, z, zz, strikes, v0, rho,
                       svW1, svb1, svW2, svb2, svW3, svb3,
                       vhW1, vhb1, vhW2, vhb2,
                       vdW1, vdb1, vdW2, vdb2,
                       vvW1, vvb1, vvW2, vvb2,
                       mats, psum, psq);

    hipLaunchKernelGGL(lsv_finalize, dim3(NPAIR), dim3(64), 0, stream,
                       psum, psq, (float*)d_out);
}

// Round 8
// 407.299 us; speedup vs baseline: 2.5174x; 1.0832x over previous
//
#include <hip/hip_runtime.h>
#include <hip/hip_bf16.h>
#include <math.h>

// ---------------------------------------------------------------------------
// LSV Monte Carlo, round 14: two-group software pipeline (intra-wave ILP).
// R13 showed occupancy is register-blocked (unified VGPR+AGPR file: 8
// waves/SIMD needs total<=64 regs -> R12's spill disaster). Ledger:
// R8=317 best | R9 363 | R10 374 | R11 356 | R13 351. The ~46% stall at
// fixed wave count is attacked with intra-wave ILP instead:
//   256 blocks x 512 threads, 64 paths = 2 groups x 32. Each wave carries
//   R8's exact role for BOTH groups, phase-offset by one interval:
//     alpha: A(G0,i)        | r3(G1,i-1)   (serial chain under G0 VALU)
//     beta : B(G0,i)        | A(G1,i)      (MFMA latency under G1 VALU)
//     gamma: C(G0,i)+folds  | B(G1,i)      (serial chain under G1 MFMA)
//   Per-path math bit-identical to R8. Barriers per path-step: 3 -> 1.5.
//   Folds/staging amortized over 2x paths. Weights (Af/Ah/epilogue) shared.
//   LDS ~78KB, 1 block/CU, 8 waves/CU; __launch_bounds__(512,2) opens the
//   register budget (residency is block-bound, pressure is free).
// ---------------------------------------------------------------------------

#define MC      16384
#define NSTEP   96
#define BLOCK   512
#define GRID    256
#define NGROUP  512          // psum slots = GRID * 2 groups
#define NPAIR   84

typedef short bf16x8 __attribute__((ext_vector_type(8)));
typedef float f32x4  __attribute__((ext_vector_type(4)));

union U8 { uint4 u; bf16x8 v; };
union BF2U { __hip_bfloat162 b; unsigned u; };

__device__ __forceinline__ unsigned bf16rne(float x) {   // setup-time only
    unsigned u = __float_as_uint(x);
    return (u + 0x7FFFu + ((u >> 16) & 1u)) >> 16;
}
__device__ __forceinline__ unsigned pk2(float lo, float hi) {
    BF2U t; t.b = __float22bfloat162_rn(make_float2(lo, hi));
    return t.u;
}
__device__ __forceinline__ float sp(float x) {
    return fmaxf(x, 0.f) + __logf(1.f + __expf(-fabsf(x)));
}

__global__ __launch_bounds__(BLOCK, 2)
void lsv_sim(const float* __restrict__ S0p,   const float* __restrict__ ratep,
             const float* __restrict__ z,     const float* __restrict__ zzg,
             const float* __restrict__ strikesg,
             const float* __restrict__ v0p,   const float* __restrict__ rhop,
             const float* __restrict__ svW1,  const float* __restrict__ svb1,
             const float* __restrict__ svW2,  const float* __restrict__ svb2,
             const float* __restrict__ svW3,  const float* __restrict__ svb3,
             const float* __restrict__ vhW1,  const float* __restrict__ vhb1,
             const float* __restrict__ vhW2,  const float* __restrict__ vhb2,
             const float* __restrict__ vdW1,  const float* __restrict__ vdb1,
             const float* __restrict__ vdW2,  const float* __restrict__ vdb2,
             const float* __restrict__ vvW1,  const float* __restrict__ vvb1,
             const float* __restrict__ vvW2,  const float* __restrict__ vvb2,
             const int*   __restrict__ mats,
             float* __restrict__ psum, float* __restrict__ psq)
{
    __shared__ __align__(16) unsigned short H1c[2][16 * 32 * 8]; // 16 KB
    __shared__ __align__(16) float W1f[16 * 32];                 // 2 KB
    __shared__ __align__(16) float WH1f[16 * 32];                // 2 KB
    __shared__ __align__(16) float B2T[128], W3T[128];           // 1 KB
    __shared__ __align__(16) float RED[2][32 * 4];               // 1 KB
    __shared__ float VDb[2][2][32], VVb[2][2][32];               // [g][buf][p]
    __shared__ float PSs[2][2][32], PSq[2][2][32];               // [g][pt][s]
    __shared__ __align__(16) float VW[128];
    __shared__ __align__(16) float4 STEP[NSTEP];                 // {t0,h,sqh,disc0}
    __shared__ float D1T[NSTEP];
    __shared__ int   ITAB[NSTEP];                                // idx | (im<<8)
    __shared__ float ZT[64][97], ZZT[64][97];                    // 49.7 KB
    __shared__ float SLOG[2][32], VST[2][32], SST[2][32], SLOGP[2][32], DSP[2][32];
    __shared__ __align__(16) float CW1[2][128];                  // t0-fold: W1
    __shared__ __align__(16) float CH[2][128];                   // t0-fold: hedge L1

    const int tid  = threadIdx.x;
    const int lane = tid & 63;
    const int w    = __builtin_amdgcn_readfirstlane(tid >> 6);   // 0..7
    const int quad = lane >> 4;
    const int col  = lane & 15;
    const int lp   = lane & 31;

    const int pt = w & 1;              // path tile within group
    const int jg = w >> 1;             // main j-group
    const int hm = w >> 1;             // hedge maturity
    const int pl = pt * 16 + col;      // path within group (0..31)
    const int kc = jg * 4 + quad;      // P1 k-chunk

    // ---- stage z/zz for all 64 paths ---------------------------------------
    {
        const size_t gbase = (size_t)blockIdx.x * 64 * NSTEP;
        for (int e = tid; e < 64 * NSTEP; e += BLOCK) {
            const int p = e / NSTEP, ii = e - p * NSTEP;
            ZT[p][ii]  = z  [gbase + e];
            ZZT[p][ii] = zzg[gbase + e];
        }
    }
    // ---- stage LDS tables --------------------------------------------------
    for (int e = tid; e < 128; e += BLOCK) {
        float v = 0.f;
        if      (e < 20)             v = vdW1[e];
        else if (e < 40)             v = vdb1[e - 20];
        else if (e < 60)             v = vdW2[e - 40];
        else if (e >= 64 && e < 84)  v = vvW1[e - 64];
        else if (e >= 84 && e < 104) v = vvb1[e - 84];
        else if (e >= 104 && e < 124)v = vvW2[e - 104];
        else if (e == 124)           v = vdb2[0];
        else if (e == 125)           v = vvb2[0];
        VW[e] = v;
        B2T[e] = (e < 100) ? svb2[e] : 0.f;
        W3T[e] = (e < 100) ? svW3[e] : 0.f;
    }
    for (int e = tid; e < 512; e += BLOCK) {       // W1f
        const int kc2 = e >> 5, r5 = e & 31, grp = r5 >> 3, kk = kc2 * 8 + (r5 & 7);
        float v = 0.f;
        if (kk < 100) v = (grp == 0) ? svW1[kk] : (grp == 1) ? svW1[100 + kk]
                        : (grp == 2) ? svW1[200 + kk] : svb1[kk];
        W1f[e] = v;
    }
    for (int e = tid; e < 512; e += BLOCK) {       // WH1f
        const int hq = e >> 5, r5 = e & 31, grp = r5 >> 3;
        const int hmm = hq >> 2, qq = hq & 3;
        const int j = qq * 8 + (r5 & 7);
        float v = 0.f;
        if (j < 20 && grp < 3)
            v = (grp == 0) ? vhW1[hmm * 40 + j] : (grp == 1) ? vhW1[hmm * 40 + 20 + j]
                                                : vhb1[hmm * 20 + j];
        WH1f[e] = v;
    }

    // ---- uniform setup -----------------------------------------------------
    const float rate  = ratep[0];
    const float S0    = S0p[0];
    const float rho_t = tanhf(rhop[0]);
    const float srho  = sqrtf(1.f - rho_t * rho_t);
    const float b3    = svb3[0];

    // ---- per-step uniform tables -------------------------------------------
    if (tid < NSTEP) {
        const int i = tid;
        const float t0 = (float)i       * (1.f / 365.f);
        const float t1 = (float)(i + 1) * (1.f / 365.f);
        const float h  = t1 - t0;
        STEP[i] = make_float4(t0, h, sqrtf(h), __expf(-rate * t0));
        D1T[i]  = __expf(-rate * t1);
        const int day = i + 1;
        const int m0 = mats[0], m1 = mats[1], m2 = mats[2], m3 = mats[3];
        const int idx = (day > m0) + (day > m1) + (day > m2);
        const int mi  = (idx == 0) ? m0 : (idx == 1) ? m1 : (idx == 2) ? m2 : m3;
        ITAB[i] = idx | ((day == mi) ? 256 : 0);
    }

    // ---- invariant A-fragments (shared across both groups) -----------------
    bf16x8 Af[4][2];
#pragma unroll
    for (int c = 0; c < 4; c++)
#pragma unroll
        for (int t = 0; t < 2; t++) {
            U8 tt;
#pragma unroll
            for (int e2 = 0; e2 < 4; e2++) {
                const int k0 = 32 * c + 8 * quad + 2 * e2;
                const int j  = (2 * jg + t) * 16 + col;
                const float v0 = (k0     < 100 && j < 100) ? svW2[k0 * 100 + j]       : 0.f;
                const float v1 = (k0 + 1 < 100 && j < 100) ? svW2[(k0 + 1) * 100 + j] : 0.f;
                (&tt.u.x)[e2] = bf16rne(v0) | (bf16rne(v1) << 16);
            }
            Af[c][t] = tt.v;
        }
    bf16x8 Ah[2];
#pragma unroll
    for (int st = 0; st < 2; st++) {
        U8 tt;
#pragma unroll
        for (int e2 = 0; e2 < 4; e2++) {
            const int j0 = 8 * quad + 2 * e2, j1 = j0 + 1;
            const int s  = st * 16 + col;
            const float v0 = (j0 < 20 && s < 21) ? vhW2[hm * 420 + j0 * 21 + s] : 0.f;
            const float v1 = (j1 < 20 && s < 21) ? vhW2[hm * 420 + j1 * 21 + s] : 0.f;
            (&tt.u.x)[e2] = bf16rne(v0) | (bf16rne(v1) << 16);
        }
        Ah[st] = tt.v;
    }
    f32x4 c0h, c1h;
    float K0a[4], K1a[4];
#pragma unroll
    for (int r = 0; r < 4; r++) {
        const int s0 = quad * 4 + r, s1 = 16 + quad * 4 + r;
        c0h[r] = vhb2[hm * 21 + s0];
        K0a[r] = strikesg[s0];
        c1h[r] = (s1 < 21) ? vhb2[hm * 21 + s1] : 0.f;
        K1a[r] = (s1 < 21) ? strikesg[s1] : 1e30f;
    }

    // ---- per-group hedge accumulators (registers) --------------------------
    f32x4 cv0A = {0.f,0.f,0.f,0.f}, cv1A = {0.f,0.f,0.f,0.f};
    f32x4 cv0B = {0.f,0.f,0.f,0.f}, cv1B = {0.f,0.f,0.f,0.f};

    __syncthreads();          // tables staged

    // ---- step-0 folds + state init (both groups) ---------------------------
    if (tid < 128) {
        const float t00 = STEP[0].x;
        const int kk = tid;
        CW1[0][kk] = fmaf(t00, W1f[(kk >> 3) * 32 + (kk & 7)],
                               W1f[(kk >> 3) * 32 + 24 + (kk & 7)]);
    } else if (tid < 256) {
        const float t00 = STEP[0].x;
        const int e = tid - 128;
        CH[0][e] = fmaf(t00, WH1f[(e >> 3) * 32 + (e & 7)],
                             WH1f[(e >> 3) * 32 + 16 + (e & 7)]);
    }
    if (tid < 64) {
        const int g = tid >> 5, p = tid & 31;
        const float Slog0 = __logf(S0);
        SLOG[g][p] = Slog0;
        SST[g][p]  = __expf(Slog0);
        VST[g][p]  = (1.f / (1.f + __expf(-v0p[0]))) * 0.5f;
    }

    __syncthreads();          // folds + state visible

    // invariant epilogue + hedge-L1 constants -> registers (shared)
    const int j0e = (2 * jg) * 16 + quad * 4;
    const float4 b2a = *reinterpret_cast<const float4*>(B2T + j0e);
    const float4 w3a = *reinterpret_cast<const float4*>(W3T + j0e);
    const float4 b2b = *reinterpret_cast<const float4*>(B2T + j0e + 16);
    const float4 w3b = *reinterpret_cast<const float4*>(W3T + j0e + 16);
    const float4 wsA = *reinterpret_cast<const float4*>(WH1f + (hm * 4 + quad) * 32 + 8);
    const float4 wsB = *reinterpret_cast<const float4*>(WH1f + (hm * 4 + quad) * 32 + 12);

    // ---- per-group work units (g is a literal at every call site) ----------
    auto p1_step = [&](int g, int buf) {
        const float slp = SLOG[g][pl];
        const float vp  = VST[g][pl];
        const float* Wp = W1f + kc * 32;
        uint4 o;
#pragma unroll
        for (int hh = 0; hh < 2; hh++) {
            const float4 b4 = *reinterpret_cast<const float4*>(Wp + 8 + hh * 4);
            const float4 c4 = *reinterpret_cast<const float4*>(Wp + 16 + hh * 4);
            const float4 cw = *reinterpret_cast<const float4*>(&CW1[buf][kc * 8 + hh * 4]);
            const float x0 = fmaxf(cw.x + slp * b4.x + vp * c4.x, 0.f);
            const float x1 = fmaxf(cw.y + slp * b4.y + vp * c4.y, 0.f);
            const float x2 = fmaxf(cw.z + slp * b4.z + vp * c4.z, 0.f);
            const float x3 = fmaxf(cw.w + slp * b4.w + vp * c4.w, 0.f);
            (&o.x)[2 * hh]     = pk2(x0, x1);
            (&o.x)[2 * hh + 1] = pk2(x2, x3);
        }
        *reinterpret_cast<uint4*>(&H1c[g][(kc * 32 + pl) * 8]) = o;
    };

    auto hedge_step = [&](int g, int ip, f32x4& cv0, f32x4& cv1) {
        const int iv   = ITAB[ip];
        const int idxp = iv & 0xff;
        if (hm >= idxp) {
            const int hb = ip & 1;
            const float slp = SLOGP[g][pl];
            U8 b;
            {
                const float4 ch4 = *reinterpret_cast<const float4*>(&CH[hb][(hm * 4 + quad) * 8]);
                (&b.u.x)[0] = pk2(fmaxf(ch4.x + slp * wsA.x, 0.f),
                                  fmaxf(ch4.y + slp * wsA.y, 0.f));
                (&b.u.x)[1] = pk2(fmaxf(ch4.z + slp * wsA.z, 0.f),
                                  fmaxf(ch4.w + slp * wsA.w, 0.f));
            }
            {
                const float4 ch4 = *reinterpret_cast<const float4*>(&CH[hb][(hm * 4 + quad) * 8 + 4]);
                (&b.u.x)[2] = pk2(fmaxf(ch4.x + slp * wsB.x, 0.f),
                                  fmaxf(ch4.y + slp * wsB.y, 0.f));
                (&b.u.x)[3] = pk2(fmaxf(ch4.z + slp * wsB.z, 0.f),
                                  fmaxf(ch4.w + slp * wsB.w, 0.f));
            }
            const f32x4 D0 = __builtin_amdgcn_mfma_f32_16x16x32_bf16(Ah[0], b.v, c0h, 0, 0, 0);
            const f32x4 D1 = __builtin_amdgcn_mfma_f32_16x16x32_bf16(Ah[1], b.v, c1h, 0, 0, 0);
            const float dsP = DSP[g][pl];
#pragma unroll
            for (int r = 0; r < 4; r++) {
                cv0[r] += sp(D0[r]) * dsP;
                cv1[r] += sp(D1[r]) * dsP;
            }
            if ((iv & 256) && hm == idxp) {
                const float Sp  = SST[g][pl];
                const float d1p = D1T[ip];
                float p0[4], q0[4], p1[4], q1[4];
#pragma unroll
                for (int r = 0; r < 4; r++) {
                    p0[r] = d1p * fmaxf(Sp - K0a[r], 0.f) - cv0[r];
                    p1[r] = d1p * fmaxf(Sp - K1a[r], 0.f) - cv1[r];
                    q0[r] = p0[r] * p0[r];
                    q1[r] = p1[r] * p1[r];
                }
#pragma unroll
                for (int o = 1; o <= 8; o <<= 1) {
#pragma unroll
                    for (int r = 0; r < 4; r++) {
                        p0[r] += __shfl_xor(p0[r], o);
                        q0[r] += __shfl_xor(q0[r], o);
                        p1[r] += __shfl_xor(p1[r], o);
                        q1[r] += __shfl_xor(q1[r], o);
                    }
                }
                if (col == 0) {
#pragma unroll
                    for (int r = 0; r < 4; r++) {
                        const int s0 = quad * 4 + r, s1 = 16 + quad * 4 + r;
                        PSs[g][pt][s0] = p0[r];  PSq[g][pt][s0] = q0[r];
                        if (s1 < 21) { PSs[g][pt][s1] = p1[r];  PSq[g][pt][s1] = q1[r]; }
                    }
                }
            }
        }
    };

    auto mfma_main = [&](int g) {
        f32x4 d0 = {0.f,0.f,0.f,0.f};
        f32x4 d1 = {0.f,0.f,0.f,0.f};
#pragma unroll
        for (int c = 0; c < 4; c++) {
            const bf16x8 b = *reinterpret_cast<const bf16x8*>(
                &H1c[g][((quad + 4 * c) * 32 + pl) * 8]);
            d0 = __builtin_amdgcn_mfma_f32_16x16x32_bf16(Af[c][0], b, d0, 0, 0, 0);
            d1 = __builtin_amdgcn_mfma_f32_16x16x32_bf16(Af[c][1], b, d1, 0, 0, 0);
        }
        float acc = fmaxf(d0[0] + b2a.x, 0.f) * w3a.x
                  + fmaxf(d0[1] + b2a.y, 0.f) * w3a.y
                  + fmaxf(d0[2] + b2a.z, 0.f) * w3a.z
                  + fmaxf(d0[3] + b2a.w, 0.f) * w3a.w
                  + fmaxf(d1[0] + b2b.x, 0.f) * w3b.x
                  + fmaxf(d1[1] + b2b.y, 0.f) * w3b.y
                  + fmaxf(d1[2] + b2b.z, 0.f) * w3b.z
                  + fmaxf(d1[3] + b2b.w, 0.f) * w3b.w;
        acc += __shfl_xor(acc, 16);
        acc += __shfl_xor(acc, 32);
        if (quad == 0)
            RED[g][pl * 4 + jg] = acc;
    };

    auto r3 = [&](int g, int i) {          // serial SDE tail, wave 1 only
        if (w == 1) {
            const float4 rr = *reinterpret_cast<const float4*>(&RED[g][lp * 4]);
            const float pout = (rr.x + rr.y) + (rr.z + rr.w);
            const float pd  = sp(pout + b3);
            const float vdv = VDb[g][i & 1][lp] + VW[124];
            const float vvv = sp(VVb[g][i & 1][lp] + VW[125]);
            const float4 u  = STEP[i];
            const float sqh = u.z;
            const float zi  = ZT[g * 32 + lp][i];
            const float zzi = ZZT[g * 32 + lp][i];
            const float dW = sqh * zi;
            const float dB = rho_t * dW + srho * sqh * zzi;
            const float Vold  = VST[g][lp];
            const float Sold  = SST[g][lp];
            const float SlogO = SLOG[g][lp];
            const float Vn = Vold + vdv * u.y + vvv * dB;
            const float drift   = rate - 0.5f * pd * pd;
            const float diff    = pd * dW;
            const float drift_c = 1.f + fabsf(drift) * sqh;
            const float diff_c  = 1.f + fabsf(pd) * sqh;
            const float Sln = SlogO + __fdividef(drift * u.y, drift_c) + __fdividef(diff, diff_c);
            const float Sn  = __expf(Sln);
            const float dS  = D1T[i] * Sn - u.w * Sold;
            if (lane < 32) {
                SLOGP[g][lp] = SlogO;  DSP[g][lp] = dS;
                SLOG[g][lp]  = Sln;    SST[g][lp] = Sn;  VST[g][lp] = Vn;
            }
        }
    };

    auto vnets = [&](int g, int buf) {     // caller picks the wave
        const float Vp = VST[g][lp];
        const float* bw = VW + ((lane >= 32) ? 64 : 0);
        float a2 = 0.f;
#pragma unroll
        for (int q5 = 0; q5 < 5; q5++) {
            const float4 w1 = *reinterpret_cast<const float4*>(bw + 4 * q5);
            const float4 b1 = *reinterpret_cast<const float4*>(bw + 20 + 4 * q5);
            const float4 w2 = *reinterpret_cast<const float4*>(bw + 40 + 4 * q5);
            a2 += fmaxf(Vp * w1.x + b1.x, 0.f) * w2.x;
            a2 += fmaxf(Vp * w1.y + b1.y, 0.f) * w2.y;
            a2 += fmaxf(Vp * w1.z + b1.z, 0.f) * w2.z;
            a2 += fmaxf(Vp * w1.w + b1.w, 0.f) * w2.w;
        }
        if (lane < 32) VDb[g][buf][lp] = a2; else VVb[g][buf][lp] = a2;
    };

    auto ps_reduce = [&](int g, int ip) {  // wave 0 only
        if (w == 0) {
            const int iv = ITAB[ip];
            if (iv & 256) {
                const int s = lane & 31;
                if (s < 21) {
                    const float* src = (lane >= 32) ? &PSq[g][0][0] : &PSs[g][0][0];
                    const float acc = src[s] + src[32 + s];
                    float* dst = (lane >= 32) ? psq : psum;
                    dst[((iv & 0xff) * 21 + s) * NGROUP + blockIdx.x * 2 + g] = acc;
                }
            }
        }
    };

    // ---- main pipeline -----------------------------------------------------
    for (int i = 0; i < NSTEP; i++) {
        const int buf = i & 1;

        // ===== interval alpha: A(G0,i) | r3(G1,i-1) =========================
        p1_step(0, buf);
        if (i > 0) {
            hedge_step(0, i - 1, cv0A, cv1A);
            r3(1, i - 1);
        }
        if (w == 0) vnets(0, buf);
        __syncthreads();

        // ===== interval beta: B(G0,i) | A(G1,i) =============================
        mfma_main(0);
        p1_step(1, buf);
        if (i > 0) {
            hedge_step(1, i - 1, cv0B, cv1B);
            ps_reduce(0, i - 1);
        }
        if (w == 1) vnets(1, buf);
        __syncthreads();

        // ===== interval gamma: C(G0,i)+folds | B(G1,i) ======================
        mfma_main(1);
        r3(0, i);
        if ((w == 2 || w == 3) && i + 1 < NSTEP) {
            const float t0n = STEP[i + 1].x;
            const int kk = (w - 2) * 64 + lane;
            CW1[buf ^ 1][kk] = fmaf(t0n, W1f[(kk >> 3) * 32 + (kk & 7)],
                                         W1f[(kk >> 3) * 32 + 24 + (kk & 7)]);
        } else if ((w == 4 || w == 5) && i + 1 < NSTEP) {
            const float t0n = STEP[i + 1].x;
            const int e = (w - 4) * 64 + lane;
            CH[buf ^ 1][e] = fmaf(t0n, WH1f[(e >> 3) * 32 + (e & 7)],
                                       WH1f[(e >> 3) * 32 + 16 + (e & 7)]);
        }
        if (i > 0) ps_reduce(1, i - 1);
        __syncthreads();
    }

    // ---- pipeline drain ----------------------------------------------------
    hedge_step(0, NSTEP - 1, cv0A, cv1A);   // uses SLOGP_G0 from gamma(95)
    r3(1, NSTEP - 1);                        // G1's final SDE step
    __syncthreads();
    ps_reduce(0, NSTEP - 1);
    hedge_step(1, NSTEP - 1, cv0B, cv1B);   // uses SLOGP_G1 from r3 above
    __syncthreads();
    ps_reduce(1, NSTEP - 1);
}

__global__ void lsv_finalize(const float* __restrict__ psum,
                             const float* __restrict__ psq,
                             float* __restrict__ out)
{
    const int t    = blockIdx.x;          // 0..NPAIR-1
    const int lane = threadIdx.x;         // 0..63
    float s = 0.f, q = 0.f;
    for (int b = lane; b < NGROUP; b += 64) {
        s += psum[t * NGROUP + b];
        q += psq [t * NGROUP + b];
    }
#pragma unroll
    for (int o = 1; o <= 32; o <<= 1) {
        s += __shfl_xor(s, o);
        q += __shfl_xor(q, o);
    }
    if (lane == 0) {
        const float mean = s * (1.0f / (float)MC);
        const float var  = (q - (float)MC * mean * mean) * (1.0f / (float)(MC - 1));
        out[t]         = mean;
        out[NPAIR + t] = var;
    }
}

extern "C" void kernel_launch(void* const* d_in, const int* in_sizes, int n_in,
                              void* d_out, int out_size, void* d_ws, size_t ws_size,
                              hipStream_t stream)
{
    const float* S0    = (const float*)d_in[0];
    const float* rate  = (const float*)d_in[1];
    const float* z     = (const float*)d_in[2];
    const float* zz    = (const float*)d_in[3];
    const float* strikes = (const float*)d_in[5];
    const float* v0    = (const float*)d_in[6];
    const float* rho   = (const float*)d_in[7];
    const float* svW1  = (const float*)d_in[8];
    const float* svb1  = (const float*)d_in[9];
    const float* svW2  = (const float*)d_in[10];
    const float* svb2  = (const float*)d_in[11];
    const float* svW3  = (const float*)d_in[12];
    const float* svb3  = (const float*)d_in[13];
    const float* vhW1  = (const float*)d_in[14];
    const float* vhb1  = (const float*)d_in[15];
    const float* vhW2  = (const float*)d_in[16];
    const float* vhb2  = (const float*)d_in[17];
    const float* vdW1  = (const float*)d_in[18];
    const float* vdb1  = (const float*)d_in[19];
    const float* vdW2  = (const float*)d_in[20];
    const float* vdb2  = (const float*)d_in[21];
    const float* vvW1  = (const float*)d_in[22];
    const float* vvb1  = (const float*)d_in[23];
    const float* vvW2  = (const float*)d_in[24];
    const float* vvb2  = (const float*)d_in[25];
    const int*   mats  = (const int*)d_in[26];

    float* psum = (float*)d_ws;
    float* psq  = psum + NPAIR * NGROUP;

    hipLaunchKernelGGL(lsv_sim, dim3(GRID), dim3(BLOCK), 0, stream,
                       S0, rate, z, zz, strikes, v0, rho,
                       svW1, svb1, svW2, svb2, svW3, svb3,
                       vhW1, vhb1, vhW2, vhb2,
                       vdW1, vdb1, vdW2, vdb2,
                       vvW1, vvb1, vvW2, vvb2,
                       mats, psum, psq);

    hipLaunchKernelGGL(lsv_finalize, dim3(NPAIR), dim3(64), 0, stream,
                       psum, psq, (float*)d_out);
}